// Round 3
// baseline (1320.670 us; speedup 1.0000x reference)
//
#include <hip/hip_runtime.h>
#include <cstdint>
#include <cstddef>

// B=2 L=2048 HIDDEN=2560 NH=16 NKV=4 HD=256 INNER=4096
// QKV combined N = 8192 (q+gate) + 1024 (k) + 1024 (v) = 10240
#define NQKV 10240

typedef __bf16 bf16;
typedef __attribute__((ext_vector_type(4))) __bf16 bvec4;
typedef __attribute__((ext_vector_type(8))) __bf16 bvec8;
typedef __attribute__((ext_vector_type(4))) float fvec4;

__device__ __forceinline__ void gll16(const bf16* g, bf16* l) {
  // async global->LDS, 16B/lane; LDS dest = wave-uniform base + lane*16
  __builtin_amdgcn_global_load_lds(
      (const __attribute__((address_space(1))) void*)g,
      (__attribute__((address_space(3))) void*)l, 16, 0, 0);
}

// ---------------- fp32 -> bf16 flat convert ----------------
__global__ __launch_bounds__(256) void cvt_f32_bf16(const float* __restrict__ x,
                                                    bf16* __restrict__ y, int n) {
  int i = (blockIdx.x * 256 + threadIdx.x) * 4;
  if (i < n) {
    float4 v = *(const float4*)(x + i);
    bvec4 o;
    o.x = (bf16)v.x; o.y = (bf16)v.y; o.z = (bf16)v.z; o.w = (bf16)v.w;
    *(bvec4*)(y + i) = o;
  }
}

// ---------------- W (K x N) fp32 -> Wt (N x K) bf16 ----------------
__global__ __launch_bounds__(256) void wtrans(const float* __restrict__ W,
                                              bf16* __restrict__ Wt, int K, int N) {
  __shared__ float t[64][65];
  int n0 = blockIdx.x * 64, k0 = blockIdx.y * 64;
  int tx = threadIdx.x & 63, tg = threadIdx.x >> 6;
#pragma unroll
  for (int i = 0; i < 16; ++i) {
    int r = tg * 16 + i;
    t[r][tx] = W[(size_t)(k0 + r) * N + n0 + tx];
  }
  __syncthreads();
#pragma unroll
  for (int i = 0; i < 16; ++i) {
    int r = tg * 16 + i;
    Wt[(size_t)(n0 + r) * K + k0 + tx] = (bf16)t[tx][r];
  }
}

// ---------------- V columns of QKV -> Vt (b,kv,d,L) bf16 ----------------
__global__ __launch_bounds__(256) void vtrans(const bf16* __restrict__ QKV,
                                              bf16* __restrict__ Vt) {
  __shared__ bf16 t[64][65];
  int l0 = blockIdx.x * 64, dd0 = blockIdx.y * 64;
  int bkv = blockIdx.z, b = bkv >> 2, kv = bkv & 3;
  int tx = threadIdx.x & 63, tg = threadIdx.x >> 6;
#pragma unroll
  for (int i = 0; i < 16; ++i) {
    int r = tg * 16 + i;
    t[r][tx] = QKV[(size_t)(b * 2048 + l0 + r) * NQKV + 9216 + kv * 256 + dd0 + tx];
  }
  __syncthreads();
#pragma unroll
  for (int i = 0; i < 16; ++i) {
    int r = tg * 16 + i;
    Vt[((size_t)bkv * 256 + dd0 + r) * 2048 + l0 + tx] = t[tx][r];
  }
}

// ---------------- RMSNorm + RoPE: QKV -> Qn (b,h,l,d), Kn (b,kv,l,d) ----------------
// Q is additionally pre-scaled by 1/sqrt(HD)=1/16 (exact in bf16) for attention.
__global__ __launch_bounds__(256) void norm_rope(const bf16* __restrict__ QKV,
    const float* __restrict__ cosT, const float* __restrict__ sinT,
    const float* __restrict__ qw, const float* __restrict__ kw,
    bf16* __restrict__ Qn, bf16* __restrict__ Kn) {
  int u = blockIdx.x * 4 + (threadIdx.x >> 6);
  int lane = threadIdx.x & 63;
  int token = u / 20, slot = u - token * 20;
  int b = token >> 11, l = token & 2047;
  int d0 = lane * 4;
  const float* w;
  int col0;
  bf16* outp;
  float post;
  if (slot < 16) {
    col0 = slot * 256; w = qw; post = 0.0625f;
    outp = Qn + ((size_t)((b * 16 + slot) * 2048 + l)) * 256;
  } else {
    int kv = slot - 16;
    col0 = 8192 + kv * 256; w = kw; post = 1.0f;
    outp = Kn + ((size_t)((b * 4 + kv) * 2048 + l)) * 256;
  }
  bvec4 xi = *(const bvec4*)(QKV + (size_t)token * NQKV + col0 + d0);
  float x[4];
#pragma unroll
  for (int j = 0; j < 4; ++j) x[j] = (float)xi[j];
  float ss = x[0] * x[0] + x[1] * x[1] + x[2] * x[2] + x[3] * x[3];
#pragma unroll
  for (int off = 32; off; off >>= 1) ss += __shfl_xor(ss, off);
  float rn = rsqrtf(ss * (1.0f / 256.0f) + 1e-6f);
  float xn[4];
#pragma unroll
  for (int j = 0; j < 4; ++j) xn[j] = x[j] * rn * w[d0 + j];
  bvec4 o;
#pragma unroll
  for (int j = 0; j < 4; ++j) {
    float other = __shfl_xor(xn[j], 32);
    float rot = (lane < 32) ? -other : other;
    float c = cosT[(size_t)l * 256 + d0 + j];
    float s = sinT[(size_t)l * 256 + d0 + j];
    o[j] = (bf16)((xn[j] * c + rot * s) * post);
  }
  *(bvec4*)(outp + d0) = o;
}

// ---------------- m97-style GEMM: C[M][N] = A[M][K] * B[N][K]^T ----------------
// 128x128 tile, BK=32. XOR-swizzled LDS: phys 8-elem chunk p at row r holds
// logical chunk p^(r&3) -> fragment b128 reads are 2-way max (free, m136).
template <typename OutT>
__global__ __launch_bounds__(256) void gemm_bt(const bf16* __restrict__ A,
                                               const bf16* __restrict__ B,
                                               OutT* __restrict__ C,
                                               int N, int Kd) {
  __shared__ alignas(16) bf16 As[4096];
  __shared__ alignas(16) bf16 Bs[4096];
  int tid = threadIdx.x, wave = tid >> 6, lane = tid & 63;
  int quad = lane >> 4, l15 = lane & 15;
  int wm = wave >> 1, wn = wave & 1;
  int m0 = blockIdx.y * 128, n0 = blockIdx.x * 128;
  const fvec4 FZ = {0.f, 0.f, 0.f, 0.f};
  fvec4 acc[4][4];
#pragma unroll
  for (int i = 0; i < 4; ++i)
#pragma unroll
    for (int j = 0; j < 4; ++j) acc[i][j] = FZ;
  int ar = lane >> 2;                              // row within 16-row segment
  int ac = ((lane & 3) ^ (ar & 3)) * 8;            // swizzled source chunk
  for (int kt = 0; kt < Kd; kt += 32) {
    __syncthreads();
#pragma unroll
    for (int i = 0; i < 2; ++i) {
      int seg = wave * 2 + i;
      int row = seg * 16 + ar;
      gll16(A + (size_t)(m0 + row) * Kd + kt + ac, As + seg * 512);
      gll16(B + (size_t)(n0 + row) * Kd + kt + ac, Bs + seg * 512);
    }
    __syncthreads();
    bvec8 af[4], bfv[4];
#pragma unroll
    for (int t = 0; t < 4; ++t) {
      int R = wm * 64 + t * 16 + l15;
      af[t]  = *(const bvec8*)(As + R * 32 + (quad ^ (R & 3)) * 8);
      int Rb = wn * 64 + t * 16 + l15;
      bfv[t] = *(const bvec8*)(Bs + Rb * 32 + (quad ^ (Rb & 3)) * 8);
    }
#pragma unroll
    for (int mt = 0; mt < 4; ++mt)
#pragma unroll
      for (int nt = 0; nt < 4; ++nt)
        acc[mt][nt] = __builtin_amdgcn_mfma_f32_16x16x32_bf16(af[mt], bfv[nt],
                                                              acc[mt][nt], 0, 0, 0);
  }
#pragma unroll
  for (int mt = 0; mt < 4; ++mt)
#pragma unroll
    for (int nt = 0; nt < 4; ++nt)
#pragma unroll
      for (int r = 0; r < 4; ++r) {
        int row = m0 + wm * 64 + mt * 16 + quad * 4 + r;
        int col = n0 + wn * 64 + nt * 16 + l15;
        C[(size_t)row * N + col] = (OutT)acc[mt][nt][r];
      }
}

// ---------------- causal flash attention v3 + SiLU-gate epilogue ----------------
// 128 threads (2 waves), wave owns 32 Q rows; Q-tile 64, K-tile 32.
// LDS: Ks 32x256 (16KB) + Vts 256x32 (16KB) + wave-private P (5KB) = 37KB
//   -> 4 blocks/CU, 8 waves/CU, 2 waves/SIMD (vs 1 in v2).
// Dedicated P => 2 barriers per k-tile (was 4). Grid longest-first (qt=31-by).
// Per-wave fully-masked tiles skip compute; alpha==1 guard skips acc rescale.
__global__ __launch_bounds__(128, 2) void flash(const bf16* __restrict__ Q,
    const bf16* __restrict__ K, const bf16* __restrict__ Vt,
    const bf16* __restrict__ QKV, bf16* __restrict__ Og) {
  __shared__ alignas(16) bf16 Ks[8192];          // 32 rows x 256, chunk^(row&31)
  __shared__ alignas(16) bf16 Vts[8192];         // 256 d-rows x 32, chunk^(row&3)
  __shared__ alignas(16) bf16 Pb[2][2][16][40];  // [wave][mt][row][col(+pad)]

  int bh = blockIdx.x, b = bh >> 4, h = bh & 15, kvh = h >> 2;
  int qt = 31 - blockIdx.y;  // longest-first dispatch
  int q0 = qt * 64;
  int tid = threadIdx.x, wave = tid >> 6, lane = tid & 63;
  int quad = lane >> 4, l15 = lane & 15;

  const bf16* Qh = Q + ((size_t)(b * 16 + h) * 2048) * 256;
  const bf16* Kb = K + ((size_t)(b * 4 + kvh) * 2048) * 256;
  const bf16* Vb = Vt + ((size_t)(b * 4 + kvh) * 256) * 2048;
  const fvec4 FZ = {0.f, 0.f, 0.f, 0.f};

  // Q fragments resident (Qn already pre-scaled by 1/16 in norm_rope)
  bvec8 qf[2][8];
#pragma unroll
  for (int mt = 0; mt < 2; ++mt) {
    int row = q0 + wave * 32 + mt * 16 + l15;
#pragma unroll
    for (int kk = 0; kk < 8; ++kk)
      qf[mt][kk] = *(const bvec8*)(Qh + (size_t)row * 256 + kk * 32 + quad * 8);
  }

  fvec4 acc[2][16];
#pragma unroll
  for (int mt = 0; mt < 2; ++mt)
#pragma unroll
    for (int i = 0; i < 16; ++i) acc[mt][i] = FZ;
  float m_run[2][4], l_run[2][4];
#pragma unroll
  for (int mt = 0; mt < 2; ++mt)
#pragma unroll
    for (int r = 0; r < 4; ++r) { m_run[mt][r] = -3.0e38f; l_run[mt][r] = 0.f; }

  int wrow0 = q0 + wave * 32;  // wave's first Q row
  int nkt = 2 * qt + 2;        // K tiles of 32 covering cols 0..q0+63
  for (int kt = 0; kt < nkt; ++kt) {
    int k0 = kt * 32;
    __syncthreads();  // prior iter's Ks/Vts readers done
#pragma unroll
    for (int i = 0; i < 8; ++i) {
      int seg = wave * 8 + i;  // 0..15 per matrix
      int krow = seg * 2 + (lane >> 5);
      gll16(Kb + (size_t)(k0 + krow) * 256 + ((lane & 31) ^ krow) * 8,
            Ks + seg * 512);
      int vrow = seg * 16 + (lane >> 2);
      gll16(Vb + (size_t)vrow * 2048 + k0 + ((lane & 3) ^ (vrow & 3)) * 8,
            Vts + seg * 512);
    }
    __syncthreads();  // tiles visible (barrier drains vmcnt)

    if (k0 <= wrow0 + 31) {  // wave-uniform: skip fully-masked tiles
      // S = Q K^T : 2 n-tiles x 8 k-steps
      fvec4 s[2][2];
#pragma unroll
      for (int nt = 0; nt < 2; ++nt) {
        s[0][nt] = FZ; s[1][nt] = FZ;
        int row = nt * 16 + l15;
#pragma unroll
        for (int ks = 0; ks < 8; ++ks) {
          bvec8 kf = *(const bvec8*)(Ks + (size_t)row * 256 +
                                     (size_t)((ks * 4 + quad) ^ row) * 8);
          s[0][nt] = __builtin_amdgcn_mfma_f32_16x16x32_bf16(qf[0][ks], kf, s[0][nt], 0, 0, 0);
          s[1][nt] = __builtin_amdgcn_mfma_f32_16x16x32_bf16(qf[1][ks], kf, s[1][nt], 0, 0, 0);
        }
      }
      if (k0 + 31 > wrow0) {  // diagonal tile: mask
#pragma unroll
        for (int mt = 0; mt < 2; ++mt)
#pragma unroll
          for (int nt = 0; nt < 2; ++nt)
#pragma unroll
            for (int r = 0; r < 4; ++r)
              if (k0 + nt * 16 + l15 > wrow0 + mt * 16 + quad * 4 + r)
                s[mt][nt][r] = -3.0e38f;
      }

      // online softmax (per mt), P into wave-private LDS (no barrier)
#pragma unroll
      for (int mt = 0; mt < 2; ++mt) {
        float alpha[4], rs[4];
        bool resc = false;
#pragma unroll
        for (int r = 0; r < 4; ++r) {
          float m = fmaxf(s[mt][0][r], s[mt][1][r]);
#pragma unroll
          for (int off = 8; off; off >>= 1) m = fmaxf(m, __shfl_xor(m, off));
          float Mn = fmaxf(m_run[mt][r], m);
          resc |= (Mn != m_run[mt][r]);
          alpha[r] = __expf(m_run[mt][r] - Mn);
          m_run[mt][r] = Mn;
          rs[r] = 0.f;
        }
#pragma unroll
        for (int nt = 0; nt < 2; ++nt)
#pragma unroll
          for (int r = 0; r < 4; ++r) {
            float pv = __expf(s[mt][nt][r] - m_run[mt][r]);
            rs[r] += pv;
            Pb[wave][mt][quad * 4 + r][nt * 16 + l15] = (bf16)pv;
          }
#pragma unroll
        for (int r = 0; r < 4; ++r) {
#pragma unroll
          for (int off = 8; off; off >>= 1) rs[r] += __shfl_xor(rs[r], off);
          l_run[mt][r] = l_run[mt][r] * alpha[r] + rs[r];
        }
        if (__any(resc)) {
#pragma unroll
          for (int nt = 0; nt < 16; ++nt)
#pragma unroll
            for (int r = 0; r < 4; ++r) acc[mt][nt][r] *= alpha[r];
        }
      }

      // O += P (2x16x32) * Vtile (32x256): one k-step, vf shared across mt
      bvec8 pf0 = *(const bvec8*)(&Pb[wave][0][l15][quad * 8]);
      bvec8 pf1 = *(const bvec8*)(&Pb[wave][1][l15][quad * 8]);
#pragma unroll
      for (int nt = 0; nt < 16; ++nt) {
        int row = nt * 16 + l15;
        bvec8 vf = *(const bvec8*)(Vts + (size_t)row * 32 +
                                   (size_t)(quad ^ (row & 3)) * 8);
        acc[0][nt] = __builtin_amdgcn_mfma_f32_16x16x32_bf16(pf0, vf, acc[0][nt], 0, 0, 0);
        acc[1][nt] = __builtin_amdgcn_mfma_f32_16x16x32_bf16(pf1, vf, acc[1][nt], 0, 0, 0);
      }
    }
  }

  // epilogue: O/l * silu(gate), token-major (b*2048+l, h*256+d)
#pragma unroll
  for (int mt = 0; mt < 2; ++mt)
#pragma unroll
    for (int r = 0; r < 4; ++r) {
      int token = b * 2048 + q0 + wave * 32 + mt * 16 + quad * 4 + r;
      float inv = 1.0f / l_run[mt][r];
#pragma unroll
      for (int nt = 0; nt < 16; ++nt) {
        int col = h * 256 + nt * 16 + l15;
        float g = (float)QKV[(size_t)token * NQKV + 4096 + col];
        float silu = g / (1.0f + __expf(-g));
        Og[(size_t)token * 4096 + col] = (bf16)(acc[mt][nt][r] * inv * silu);
      }
    }
}

extern "C" void kernel_launch(void* const* d_in, const int* in_sizes, int n_in,
                              void* d_out, int out_size, void* d_ws, size_t ws_size,
                              hipStream_t stream) {
  const float* hs   = (const float*)d_in[0];
  const float* cosT = (const float*)d_in[1];
  const float* sinT = (const float*)d_in[2];
  const float* Wq   = (const float*)d_in[3];
  const float* Wk   = (const float*)d_in[4];
  const float* Wv   = (const float*)d_in[5];
  const float* Wo   = (const float*)d_in[6];
  const float* qw   = (const float*)d_in[7];
  const float* kw   = (const float*)d_in[8];
  float* out = (float*)d_out;

  char* p = (char*)d_ws;
  auto alloc = [&](size_t bytes) {
    char* r = p;
    p += (bytes + 255) & ~(size_t)255;
    return r;
  };
  bf16* Xb    = (bf16*)alloc((size_t)4096 * 2560 * 2);
  bf16* Wqkvt = (bf16*)alloc((size_t)10240 * 2560 * 2);
  bf16* Wot   = (bf16*)alloc((size_t)2560 * 4096 * 2);
  bf16* QKV   = (bf16*)alloc((size_t)4096 * 10240 * 2);
  bf16* Qn    = (bf16*)alloc((size_t)2 * 16 * 2048 * 256 * 2);
  bf16* Kn    = (bf16*)alloc((size_t)2 * 4 * 2048 * 256 * 2);
  bf16* Vtb   = (bf16*)alloc((size_t)2 * 4 * 256 * 2048 * 2);
  bf16* Og    = (bf16*)alloc((size_t)4096 * 4096 * 2);

  cvt_f32_bf16<<<10240, 256, 0, stream>>>(hs, Xb, 4096 * 2560);
  wtrans<<<dim3(128, 40), 256, 0, stream>>>(Wq, Wqkvt, 2560, 8192);
  wtrans<<<dim3(16, 40), 256, 0, stream>>>(Wk, Wqkvt + (size_t)8192 * 2560, 2560, 1024);
  wtrans<<<dim3(16, 40), 256, 0, stream>>>(Wv, Wqkvt + (size_t)9216 * 2560, 2560, 1024);
  wtrans<<<dim3(40, 64), 256, 0, stream>>>(Wo, Wot, 4096, 2560);

  gemm_bt<bf16><<<dim3(80, 32), 256, 0, stream>>>(Xb, Wqkvt, QKV, 10240, 2560);

  norm_rope<<<20480, 256, 0, stream>>>(QKV, cosT, sinT, qw, kw, Qn, Kn);
  vtrans<<<dim3(32, 4, 8), 256, 0, stream>>>(QKV, Vtb);

  flash<<<dim3(32, 32), 128, 0, stream>>>(Qn, Kn, Vtb, QKV, Og);

  gemm_bt<float><<<dim3(20, 32), 256, 0, stream>>>(Og, Wot, out, 2560, 4096);
}

// Round 4
// 941.450 us; speedup vs baseline: 1.4028x; 1.4028x over previous
//
#include <hip/hip_runtime.h>
#include <cstdint>
#include <cstddef>

// B=2 L=2048 HIDDEN=2560 NH=16 NKV=4 HD=256 INNER=4096
// QKV combined N = 8192 (q+gate) + 1024 (k) + 1024 (v) = 10240
#define NQKV 10240

typedef __bf16 bf16;
typedef __attribute__((ext_vector_type(4))) __bf16 bvec4;
typedef __attribute__((ext_vector_type(8))) __bf16 bvec8;
typedef __attribute__((ext_vector_type(4))) float fvec4;

__device__ __forceinline__ void gll16(const bf16* g, bf16* l) {
  // async global->LDS, 16B/lane; LDS dest = wave-uniform base + lane*16
  __builtin_amdgcn_global_load_lds(
      (const __attribute__((address_space(1))) void*)g,
      (__attribute__((address_space(3))) void*)l, 16, 0, 0);
}

// ---------------- fp32 -> bf16 flat convert ----------------
__global__ __launch_bounds__(256) void cvt_f32_bf16(const float* __restrict__ x,
                                                    bf16* __restrict__ y, int n) {
  int i = (blockIdx.x * 256 + threadIdx.x) * 4;
  if (i < n) {
    float4 v = *(const float4*)(x + i);
    bvec4 o;
    o.x = (bf16)v.x; o.y = (bf16)v.y; o.z = (bf16)v.z; o.w = (bf16)v.w;
    *(bvec4*)(y + i) = o;
  }
}

// ---------------- W (K x N) fp32 -> Wt (N x K) bf16 ----------------
__global__ __launch_bounds__(256) void wtrans(const float* __restrict__ W,
                                              bf16* __restrict__ Wt, int K, int N) {
  __shared__ float t[64][65];
  int n0 = blockIdx.x * 64, k0 = blockIdx.y * 64;
  int tx = threadIdx.x & 63, tg = threadIdx.x >> 6;
#pragma unroll
  for (int i = 0; i < 16; ++i) {
    int r = tg * 16 + i;
    t[r][tx] = W[(size_t)(k0 + r) * N + n0 + tx];
  }
  __syncthreads();
#pragma unroll
  for (int i = 0; i < 16; ++i) {
    int r = tg * 16 + i;
    Wt[(size_t)(n0 + r) * K + k0 + tx] = (bf16)t[tx][r];
  }
}

// ---------------- V columns of QKV -> Vt (b,kv,d,L) bf16 ----------------
__global__ __launch_bounds__(256) void vtrans(const bf16* __restrict__ QKV,
                                              bf16* __restrict__ Vt) {
  __shared__ bf16 t[64][65];
  int l0 = blockIdx.x * 64, dd0 = blockIdx.y * 64;
  int bkv = blockIdx.z, b = bkv >> 2, kv = bkv & 3;
  int tx = threadIdx.x & 63, tg = threadIdx.x >> 6;
#pragma unroll
  for (int i = 0; i < 16; ++i) {
    int r = tg * 16 + i;
    t[r][tx] = QKV[(size_t)(b * 2048 + l0 + r) * NQKV + 9216 + kv * 256 + dd0 + tx];
  }
  __syncthreads();
#pragma unroll
  for (int i = 0; i < 16; ++i) {
    int r = tg * 16 + i;
    Vt[((size_t)bkv * 256 + dd0 + r) * 2048 + l0 + tx] = t[tx][r];
  }
}

// ---------------- RMSNorm + RoPE: QKV -> Qn (b,h,l,d), Kn (b,kv,l,d) ----------------
// Q is additionally pre-scaled by 1/sqrt(HD)=1/16 (exact in bf16) for attention.
__global__ __launch_bounds__(256) void norm_rope(const bf16* __restrict__ QKV,
    const float* __restrict__ cosT, const float* __restrict__ sinT,
    const float* __restrict__ qw, const float* __restrict__ kw,
    bf16* __restrict__ Qn, bf16* __restrict__ Kn) {
  int u = blockIdx.x * 4 + (threadIdx.x >> 6);
  int lane = threadIdx.x & 63;
  int token = u / 20, slot = u - token * 20;
  int b = token >> 11, l = token & 2047;
  int d0 = lane * 4;
  const float* w;
  int col0;
  bf16* outp;
  float post;
  if (slot < 16) {
    col0 = slot * 256; w = qw; post = 0.0625f;
    outp = Qn + ((size_t)((b * 16 + slot) * 2048 + l)) * 256;
  } else {
    int kv = slot - 16;
    col0 = 8192 + kv * 256; w = kw; post = 1.0f;
    outp = Kn + ((size_t)((b * 4 + kv) * 2048 + l)) * 256;
  }
  bvec4 xi = *(const bvec4*)(QKV + (size_t)token * NQKV + col0 + d0);
  float x[4];
#pragma unroll
  for (int j = 0; j < 4; ++j) x[j] = (float)xi[j];
  float ss = x[0] * x[0] + x[1] * x[1] + x[2] * x[2] + x[3] * x[3];
#pragma unroll
  for (int off = 32; off; off >>= 1) ss += __shfl_xor(ss, off);
  float rn = rsqrtf(ss * (1.0f / 256.0f) + 1e-6f);
  float xn[4];
#pragma unroll
  for (int j = 0; j < 4; ++j) xn[j] = x[j] * rn * w[d0 + j];
  bvec4 o;
#pragma unroll
  for (int j = 0; j < 4; ++j) {
    float other = __shfl_xor(xn[j], 32);
    float rot = (lane < 32) ? -other : other;
    float c = cosT[(size_t)l * 256 + d0 + j];
    float s = sinT[(size_t)l * 256 + d0 + j];
    o[j] = (bf16)((xn[j] * c + rot * s) * post);
  }
  *(bvec4*)(outp + d0) = o;
}

// ---------------- m97-style GEMM: C[M][N] = A[M][K] * B[N][K]^T ----------------
// 128x128 tile, BK=32. XOR-swizzled LDS: phys 8-elem chunk p at row r holds
// logical chunk p^(r&3) -> fragment b128 reads are 2-way max (free, m136).
template <typename OutT>
__global__ __launch_bounds__(256) void gemm_bt(const bf16* __restrict__ A,
                                               const bf16* __restrict__ B,
                                               OutT* __restrict__ C,
                                               int N, int Kd) {
  __shared__ alignas(16) bf16 As[4096];
  __shared__ alignas(16) bf16 Bs[4096];
  int tid = threadIdx.x, wave = tid >> 6, lane = tid & 63;
  int quad = lane >> 4, l15 = lane & 15;
  int wm = wave >> 1, wn = wave & 1;
  int m0 = blockIdx.y * 128, n0 = blockIdx.x * 128;
  const fvec4 FZ = {0.f, 0.f, 0.f, 0.f};
  fvec4 acc[4][4];
#pragma unroll
  for (int i = 0; i < 4; ++i)
#pragma unroll
    for (int j = 0; j < 4; ++j) acc[i][j] = FZ;
  int ar = lane >> 2;                              // row within 16-row segment
  int ac = ((lane & 3) ^ (ar & 3)) * 8;            // swizzled source chunk
  for (int kt = 0; kt < Kd; kt += 32) {
    __syncthreads();
#pragma unroll
    for (int i = 0; i < 2; ++i) {
      int seg = wave * 2 + i;
      int row = seg * 16 + ar;
      gll16(A + (size_t)(m0 + row) * Kd + kt + ac, As + seg * 512);
      gll16(B + (size_t)(n0 + row) * Kd + kt + ac, Bs + seg * 512);
    }
    __syncthreads();
    bvec8 af[4], bfv[4];
#pragma unroll
    for (int t = 0; t < 4; ++t) {
      int R = wm * 64 + t * 16 + l15;
      af[t]  = *(const bvec8*)(As + R * 32 + (quad ^ (R & 3)) * 8);
      int Rb = wn * 64 + t * 16 + l15;
      bfv[t] = *(const bvec8*)(Bs + Rb * 32 + (quad ^ (Rb & 3)) * 8);
    }
#pragma unroll
    for (int mt = 0; mt < 4; ++mt)
#pragma unroll
      for (int nt = 0; nt < 4; ++nt)
        acc[mt][nt] = __builtin_amdgcn_mfma_f32_16x16x32_bf16(af[mt], bfv[nt],
                                                              acc[mt][nt], 0, 0, 0);
  }
#pragma unroll
  for (int mt = 0; mt < 4; ++mt)
#pragma unroll
    for (int nt = 0; nt < 4; ++nt)
#pragma unroll
      for (int r = 0; r < 4; ++r) {
        int row = m0 + wm * 64 + mt * 16 + quad * 4 + r;
        int col = n0 + wn * 64 + nt * 16 + l15;
        C[(size_t)row * N + col] = (OutT)acc[mt][nt][r];
      }
}

// ---------------- causal flash attention v4 + SiLU-gate epilogue ----------------
// (v2 structure restored — it measured ~250us — plus alpha-guard and
//  pre-scaled Q.)
// Block = 128 threads (2 waves), wave owns 32 Q rows (2 m-tiles). Q-tile 64,
// K-tile 64. Pairing (i, 31-i): every block runs exactly 33 k-tiles; grid
// (16 pairs, 32 bh) with bh on the SLOW dim -> co-located blocks share K/V
// (r3 lesson: bh-fast destroyed L2 reuse, FETCH 98->806 MB).
// XOR-swizzled staging: Ks chunk^(row&31), Vts chunk^(row&7); P aliases Ks
// after a barrier (2x16x72 per wave).
__global__ __launch_bounds__(128, 1) void flash(const bf16* __restrict__ Q,
    const bf16* __restrict__ K, const bf16* __restrict__ Vt,
    const bf16* __restrict__ QKV, bf16* __restrict__ Og) {
  __shared__ alignas(16) bf16 smem[32768];
  bf16* Ks = smem;
  bf16* Vts = smem + 16384;

  int pairi = blockIdx.x;  // 0..15 (fast dim: same-bh blocks adjacent)
  int bh = blockIdx.y, b = bh >> 4, h = bh & 15, kvh = h >> 2;
  int tid = threadIdx.x, wave = tid >> 6, lane = tid & 63;
  int quad = lane >> 4, l15 = lane & 15;

  const bf16* Qh = Q + ((size_t)(b * 16 + h) * 2048) * 256;
  const bf16* Kb = K + ((size_t)(b * 4 + kvh) * 2048) * 256;
  const bf16* Vb = Vt + ((size_t)(b * 4 + kvh) * 256) * 2048;
  const fvec4 FZ = {0.f, 0.f, 0.f, 0.f};

  for (int half = 0; half < 2; ++half) {
    int qt = half ? (31 - pairi) : pairi;
    int q0 = qt * 64;

    // Q fragments resident (Qn already pre-scaled by 1/16 in norm_rope)
    bvec8 qf[2][8];
#pragma unroll
    for (int mt = 0; mt < 2; ++mt) {
      int row = q0 + wave * 32 + mt * 16 + l15;
#pragma unroll
      for (int kk = 0; kk < 8; ++kk)
        qf[mt][kk] = *(const bvec8*)(Qh + (size_t)row * 256 + kk * 32 + quad * 8);
    }

    fvec4 acc[2][16];
#pragma unroll
    for (int mt = 0; mt < 2; ++mt)
#pragma unroll
      for (int i = 0; i < 16; ++i) acc[mt][i] = FZ;
    float m_run[2][4], l_run[2][4];
#pragma unroll
    for (int mt = 0; mt < 2; ++mt)
#pragma unroll
      for (int r = 0; r < 4; ++r) { m_run[mt][r] = -3.0e38f; l_run[mt][r] = 0.f; }

    for (int kt = 0; kt <= qt; ++kt) {
      int k0 = kt * 64;
      __syncthreads();  // prior iter's LDS readers done before restaging
#pragma unroll
      for (int i = 0; i < 16; ++i) {
        int seg = wave * 16 + i;  // 0..31, 1KB per gll16
        int krow = seg * 2 + (lane >> 5);
        int kc = (lane & 31) ^ (krow & 31);
        gll16(Kb + (size_t)(k0 + krow) * 256 + kc * 8, Ks + seg * 512);
        int vrow = seg * 8 + (lane >> 3);
        int vc = (lane & 7) ^ (vrow & 7);
        gll16(Vb + (size_t)vrow * 2048 + k0 + vc * 8, Vts + seg * 512);
      }
      __syncthreads();  // tiles visible (barrier drains vmcnt)

      // S = Q K^T; kf shared across the 2 m-tiles
      fvec4 s[2][4];
#pragma unroll
      for (int nt = 0; nt < 4; ++nt) {
        s[0][nt] = FZ; s[1][nt] = FZ;
        int row = nt * 16 + l15;
        int rm = row & 31;
#pragma unroll
        for (int ks = 0; ks < 8; ++ks) {
          int c = ks * 4 + quad;
          bvec8 kf = *(const bvec8*)(Ks + (size_t)row * 256 + (size_t)(c ^ rm) * 8);
          s[0][nt] = __builtin_amdgcn_mfma_f32_16x16x32_bf16(qf[0][ks], kf, s[0][nt], 0, 0, 0);
          s[1][nt] = __builtin_amdgcn_mfma_f32_16x16x32_bf16(qf[1][ks], kf, s[1][nt], 0, 0, 0);
        }
      }
      __syncthreads();  // ALL waves' Ks reads done -> P may alias Ks

      if (kt == qt) {  // only the diagonal tile masks
#pragma unroll
        for (int mt = 0; mt < 2; ++mt)
#pragma unroll
          for (int nt = 0; nt < 4; ++nt)
#pragma unroll
            for (int r = 0; r < 4; ++r)
              if (k0 + nt * 16 + l15 > q0 + wave * 32 + mt * 16 + quad * 4 + r)
                s[mt][nt][r] = -3.0e38f;
      }

      bf16* Pw = smem + wave * 2304;  // 2 x 16 x 72 bf16, aliases Ks
#pragma unroll
      for (int mt = 0; mt < 2; ++mt) {
        float alpha[4], rs[4];
        bool resc = false;
#pragma unroll
        for (int r = 0; r < 4; ++r) {
          float m = fmaxf(fmaxf(s[mt][0][r], s[mt][1][r]),
                          fmaxf(s[mt][2][r], s[mt][3][r]));
#pragma unroll
          for (int off = 8; off; off >>= 1) m = fmaxf(m, __shfl_xor(m, off));
          float Mn = fmaxf(m_run[mt][r], m);
          resc |= (Mn != m_run[mt][r]);
          alpha[r] = __expf(m_run[mt][r] - Mn);
          m_run[mt][r] = Mn;
          rs[r] = 0.f;
        }
#pragma unroll
        for (int nt = 0; nt < 4; ++nt)
#pragma unroll
          for (int r = 0; r < 4; ++r) {
            float p = __expf(s[mt][nt][r] - m_run[mt][r]);
            rs[r] += p;
            Pw[mt * 1152 + (quad * 4 + r) * 72 + nt * 16 + l15] = (bf16)p;
          }
#pragma unroll
        for (int r = 0; r < 4; ++r) {
#pragma unroll
          for (int off = 8; off; off >>= 1) rs[r] += __shfl_xor(rs[r], off);
          l_run[mt][r] = l_run[mt][r] * alpha[r] + rs[r];
        }
        if (__any(resc)) {  // skip 128-mult rescale once running max stable
#pragma unroll
          for (int nt = 0; nt < 16; ++nt)
#pragma unroll
            for (int r = 0; r < 4; ++r) acc[mt][nt][r] *= alpha[r];
        }
      }
      __syncthreads();  // P writes visible

      // O += P (2x16x64) * Vtile (64x256); vf shared across the 2 m-tiles
#pragma unroll
      for (int ks = 0; ks < 2; ++ks) {
        bvec8 pf0 = *(const bvec8*)(Pw + l15 * 72 + ks * 32 + quad * 8);
        bvec8 pf1 = *(const bvec8*)(Pw + 1152 + l15 * 72 + ks * 32 + quad * 8);
#pragma unroll
        for (int nt = 0; nt < 16; ++nt) {
          int row = nt * 16 + l15;
          int c = ks * 4 + quad;
          bvec8 vf = *(const bvec8*)(Vts + (size_t)row * 64 + (size_t)(c ^ (row & 7)) * 8);
          acc[0][nt] = __builtin_amdgcn_mfma_f32_16x16x32_bf16(pf0, vf, acc[0][nt], 0, 0, 0);
          acc[1][nt] = __builtin_amdgcn_mfma_f32_16x16x32_bf16(pf1, vf, acc[1][nt], 0, 0, 0);
        }
      }
    }

    // epilogue: O/l * silu(gate), token-major (b*2048+l, h*256+d)
#pragma unroll
    for (int mt = 0; mt < 2; ++mt)
#pragma unroll
      for (int r = 0; r < 4; ++r) {
        int token = b * 2048 + q0 + wave * 32 + mt * 16 + quad * 4 + r;
        float inv = 1.0f / l_run[mt][r];
#pragma unroll
        for (int nt = 0; nt < 16; ++nt) {
          int col = h * 256 + nt * 16 + l15;
          float g = (float)QKV[(size_t)token * NQKV + 4096 + col];
          float silu = g / (1.0f + __expf(-g));
          Og[(size_t)token * 4096 + col] = (bf16)(acc[mt][nt][r] * inv * silu);
        }
      }
  }
}

extern "C" void kernel_launch(void* const* d_in, const int* in_sizes, int n_in,
                              void* d_out, int out_size, void* d_ws, size_t ws_size,
                              hipStream_t stream) {
  const float* hs   = (const float*)d_in[0];
  const float* cosT = (const float*)d_in[1];
  const float* sinT = (const float*)d_in[2];
  const float* Wq   = (const float*)d_in[3];
  const float* Wk   = (const float*)d_in[4];
  const float* Wv   = (const float*)d_in[5];
  const float* Wo   = (const float*)d_in[6];
  const float* qw   = (const float*)d_in[7];
  const float* kw   = (const float*)d_in[8];
  float* out = (float*)d_out;

  char* p = (char*)d_ws;
  auto alloc = [&](size_t bytes) {
    char* r = p;
    p += (bytes + 255) & ~(size_t)255;
    return r;
  };
  bf16* Xb    = (bf16*)alloc((size_t)4096 * 2560 * 2);
  bf16* Wqkvt = (bf16*)alloc((size_t)10240 * 2560 * 2);
  bf16* Wot   = (bf16*)alloc((size_t)2560 * 4096 * 2);
  bf16* QKV   = (bf16*)alloc((size_t)4096 * 10240 * 2);
  bf16* Qn    = (bf16*)alloc((size_t)2 * 16 * 2048 * 256 * 2);
  bf16* Kn    = (bf16*)alloc((size_t)2 * 4 * 2048 * 256 * 2);
  bf16* Vtb   = (bf16*)alloc((size_t)2 * 4 * 256 * 2048 * 2);
  bf16* Og    = (bf16*)alloc((size_t)4096 * 4096 * 2);

  cvt_f32_bf16<<<10240, 256, 0, stream>>>(hs, Xb, 4096 * 2560);
  wtrans<<<dim3(128, 40), 256, 0, stream>>>(Wq, Wqkvt, 2560, 8192);
  wtrans<<<dim3(16, 40), 256, 0, stream>>>(Wk, Wqkvt + (size_t)8192 * 2560, 2560, 1024);
  wtrans<<<dim3(16, 40), 256, 0, stream>>>(Wv, Wqkvt + (size_t)9216 * 2560, 2560, 1024);
  wtrans<<<dim3(40, 64), 256, 0, stream>>>(Wo, Wot, 4096, 2560);

  gemm_bt<bf16><<<dim3(80, 32), 256, 0, stream>>>(Xb, Wqkvt, QKV, 10240, 2560);

  norm_rope<<<20480, 256, 0, stream>>>(QKV, cosT, sinT, qw, kw, Qn, Kn);
  vtrans<<<dim3(32, 4, 8), 256, 0, stream>>>(QKV, Vtb);

  flash<<<dim3(16, 32), 128, 0, stream>>>(Qn, Kn, Vtb, QKV, Og);

  gemm_bt<float><<<dim3(20, 32), 256, 0, stream>>>(Og, Wot, out, 2560, 4096);
}